// Round 3
// baseline (525.152 us; speedup 1.0000x reference)
//
#include <hip/hip_runtime.h>
#include <hip/hip_bf16.h>

// EMD loss: out[row] = sum_j ( cumsum_j(x - y) )^2, rows=262144, bins=256.
// Memory-bound: 512 MiB in / 1 MiB out -> ~85us floor at 6.3 TB/s.
//
// Thread-per-row design: zero cross-lane ops (the previous wave-per-row
// version spent ~500 dependent cycles/row in ds_bpermute shuffle chains).
// Each thread walks its row with 64 float4 loads per input; the serial
// prefix sum + fma(s,s,acc) runs on the VALU at negligible cost.
// #pragma unroll 8 issues the 4 float4s of each 64B line back-to-back so
// the L1/MSHRs merge them -> no HBM over-fetch despite the 1KiB lane stride.

__global__ __launch_bounds__(256) void emd_loss_rowthread(
    const float* __restrict__ x,
    const float* __restrict__ y,
    float* __restrict__ out,
    int nrows) {
  const int row = blockIdx.x * blockDim.x + threadIdx.x;
  if (row >= nrows) return;

  const float4* __restrict__ xr =
      reinterpret_cast<const float4*>(x + (size_t)row * 256);
  const float4* __restrict__ yr =
      reinterpret_cast<const float4*>(y + (size_t)row * 256);

  float s = 0.0f;    // running prefix of (x - y)
  float acc = 0.0f;  // sum of squares of the prefix

#pragma unroll 8
  for (int k = 0; k < 64; ++k) {
    const float4 xv = xr[k];
    const float4 yv = yr[k];
    s += xv.x - yv.x; acc = fmaf(s, s, acc);
    s += xv.y - yv.y; acc = fmaf(s, s, acc);
    s += xv.z - yv.z; acc = fmaf(s, s, acc);
    s += xv.w - yv.w; acc = fmaf(s, s, acc);
  }

  out[row] = acc;  // fully coalesced store
}

extern "C" void kernel_launch(void* const* d_in, const int* in_sizes, int n_in,
                              void* d_out, int out_size, void* d_ws, size_t ws_size,
                              hipStream_t stream) {
  const float* x = (const float*)d_in[0];
  const float* y = (const float*)d_in[1];
  float* out = (float*)d_out;
  const int nrows = in_sizes[0] / 256;  // 262144

  const int block = 256;
  const int grid = (nrows + block - 1) / block;  // 1024 blocks, one thread/row
  emd_loss_rowthread<<<grid, block, 0, stream>>>(x, y, out, nrows);
}